// Round 10
// baseline (306.297 us; speedup 1.0000x reference)
//
#include <hip/hip_runtime.h>
#include <hip/hip_bf16.h>
#include <stdint.h>

typedef __attribute__((ext_vector_type(8))) short s16x8;
typedef __attribute__((ext_vector_type(4))) short s16x4;
typedef __attribute__((ext_vector_type(4))) float f32x4;

#define T_   2048
#define NH   16
#define HD   64
#define DIN  1024
#define SCALE_LOG2 0.18033688011112042f  // (1/8)*log2(e)

#define MFMA32(a, b, c) __builtin_amdgcn_mfma_f32_16x16x32_bf16(a, b, c, 0, 0, 0)

// True K=16 bf16 MFMA when available (gfx950 has v_mfma_f32_16x16x16_bf16);
// fallback: zero-padded K=32 emulation (correct, half-rate) so the host pass
// always compiles.
__device__ __forceinline__ f32x4 mfma16(s16x4 a, s16x4 b, f32x4 c) {
#if __has_builtin(__builtin_amdgcn_mfma_f32_16x16x16bf16_1k)
  return __builtin_amdgcn_mfma_f32_16x16x16bf16_1k(a, b, c, 0, 0, 0);
#else
  s16x8 a8 = {a[0], a[1], a[2], a[3], 0, 0, 0, 0};
  s16x8 b8 = {b[0], b[1], b[2], b[3], 0, 0, 0, 0};
  return __builtin_amdgcn_mfma_f32_16x16x32_bf16(a8, b8, c, 0, 0, 0);
#endif
}

// RTNE fp32 -> bf16
__device__ __forceinline__ unsigned short f2bf(float f) {
  union { float f; uint32_t u; } c; c.f = f;
  uint32_t u = c.u;
  return (unsigned short)((u + 0x7FFFu + ((u >> 16) & 1u)) >> 16);
}

__device__ __forceinline__ uint32_t pk_bf16(float a, float b) {
  __hip_bfloat162 h = __float22bfloat162_rn(make_float2(a, b));
  return *reinterpret_cast<uint32_t*>(&h);
}

// async global->LDS, 16B per lane (GEMM staging)
#define GLL(gp, lp) __builtin_amdgcn_global_load_lds( \
    (__attribute__((address_space(1))) void*)(gp),    \
    (__attribute__((address_space(3))) void*)(lp), 16, 0, 0)

// ---------------- kernel 1: fp32 -> bf16 conversion ----------------
__global__ __launch_bounds__(256) void cvt_kernel(
    const float* __restrict__ x,  const float* __restrict__ wq,
    const float* __restrict__ wk, const float* __restrict__ wv,
    unsigned short* __restrict__ xb, unsigned short* __restrict__ wb) {
  int i = (blockIdx.x * 256 + threadIdx.x) * 4;
  float4 v;
  unsigned short* dp;
  if (i < 4194304) {
    v = *(const float4*)(x + i);
    dp = xb + i;
  } else {
    int j = i - 4194304;
    int seg = j >> 20, r = j & 1048575;
    const float* w = (seg == 0) ? wq : (seg == 1) ? wk : wv;
    v = *(const float4*)(w + r);
    dp = wb + j;
  }
  ushort4 o;
  o.x = f2bf(v.x); o.y = f2bf(v.y); o.z = f2bf(v.z); o.w = f2bf(v.w);
  *(ushort4*)dp = o;
}

// ---------------- kernel 2: QKV projection GEMM (round-7, unchanged) -------
__global__ __launch_bounds__(256) void qkv_gemm(
    const unsigned short* __restrict__ A, const unsigned short* __restrict__ Bm,
    unsigned short* __restrict__ qkv) {
  __shared__ __attribute__((aligned(16))) unsigned short Alds[128 * 64];
  __shared__ __attribute__((aligned(16))) unsigned short Blds[128 * 64];
  const int tid = threadIdx.x;
  const int lane = tid & 63, wave = tid >> 6;
  const int wm = wave >> 1, wn = wave & 1;
  const int m0 = blockIdx.y * 128, n0 = blockIdx.x * 128;

  f32x4 acc[4][4] = {};

  const int srow = wave * 32 + (lane >> 3);
  const int scol = (((lane & 7) ^ ((lane >> 3) & 7))) * 8;
  const unsigned short* ag = A  + (size_t)(m0 + srow) * DIN + scol;
  const unsigned short* bg = Bm + (size_t)(n0 + srow) * DIN + scol;
  unsigned short* al = &Alds[wave * 32 * 64];
  unsigned short* bl = &Blds[wave * 32 * 64];

  const int l16 = lane & 15, quad = lane >> 4;
  const int sw = l16 & 7;

  for (int k0 = 0; k0 < DIN; k0 += 64) {
    __syncthreads();
#pragma unroll
    for (int i = 0; i < 4; i++) {
      GLL(ag + (size_t)i * 8 * DIN + k0, al + i * 512);
      GLL(bg + (size_t)i * 8 * DIN + k0, bl + i * 512);
    }
    __syncthreads();
#pragma unroll
    for (int ks = 0; ks < 2; ks++) {
      const int cl = ((ks * 4 + quad) ^ sw) * 8;
      s16x8 af[4], bf[4];
#pragma unroll
      for (int mt = 0; mt < 4; mt++)
        af[mt] = *(const s16x8*)&Alds[(wm * 64 + mt * 16 + l16) * 64 + cl];
#pragma unroll
      for (int nt = 0; nt < 4; nt++)
        bf[nt] = *(const s16x8*)&Blds[(wn * 64 + nt * 16 + l16) * 64 + cl];
#pragma unroll
      for (int mt = 0; mt < 4; mt++)
#pragma unroll
        for (int nt = 0; nt < 4; nt++)
          acc[mt][nt] = MFMA32(af[mt], bf[nt], acc[mt][nt]);
    }
  }

#pragma unroll
  for (int mt = 0; mt < 4; mt++) {
    int mbase = m0 + wm * 64 + mt * 16 + (quad << 2);
    int b = mbase >> 11, t = mbase & 2047;
#pragma unroll
    for (int nt = 0; nt < 4; nt++) {
      int n = n0 + wn * 64 + nt * 16 + l16;
      int sel = n >> 10, h = (n >> 6) & 15, d = n & 63;
      int bh = b * NH + h;
      if (sel == 2) {
        ushort4 pk;
        pk.x = f2bf(acc[mt][nt][0]); pk.y = f2bf(acc[mt][nt][1]);
        pk.z = f2bf(acc[mt][nt][2]); pk.w = f2bf(acc[mt][nt][3]);
        *(ushort4*)&qkv[8388608 + (size_t)(bh * HD + d) * T_ + t] = pk;
      } else {
        float qs = (sel == 0) ? SCALE_LOG2 : 1.f;
#pragma unroll
        for (int r = 0; r < 4; r++)
          qkv[(size_t)sel * 4194304 + (size_t)(bh * T_ + t + r) * HD + d] =
              f2bf(acc[mt][nt][r] * qs);
      }
    }
  }
}

// ---------------- kernel 3: LDS-free barrier-free flash attention ----------
// 64-q blocks (grid bh x qt-desc); wave w owns q rows [q0+16w, q0+16w+16),
// all keys. Everything in registers:
//  - S^T = K·Q^T via MFMA32 (A=K frags loaded direct from global, software-
//    pipelined in place; B=Q regs). s[nt][r] = S^T[key=nt*16+quad*4+r][q=l16].
//  - That IS the K=16 A-operand layout (m=l16, k=quad*4+j) -> P = exp2(S)
//    feeds PV directly from registers. PV/l-sums use true K=16 MFMA.
//  - V^T[d][t] b64 frags direct from global (one cache line per d-row/tile,
//    reused 16x within the iter; L1-resident across the block's 4 waves).
// No LDS, no __syncthreads anywhere.
__global__ __launch_bounds__(256) void attn_kernel(
    const unsigned short* __restrict__ qkv, float* __restrict__ out) {
  const int lane = threadIdx.x & 63, wave = threadIdx.x >> 6;
  const int l16 = lane & 15, quad = lane >> 4;
  const int qt = 31 - blockIdx.y, bh = blockIdx.x;
  const int q0 = qt * 64;
  const size_t bh_off = (size_t)bh * (T_ * HD);
  const unsigned short* Q  = qkv + bh_off;            // [t][d], pre-scaled
  const unsigned short* Kb = qkv + 4194304 + bh_off;  // [t][d]
  const unsigned short* Vb = qkv + 8388608 + bh_off;  // [d][t]

  // Q frags: B-operand (n=q=l16 of this wave's 16 rows, k=d)
  s16x8 qf[2];
  {
    const unsigned short* qp =
        Q + (size_t)(q0 + wave * 16 + l16) * HD + quad * 8;
    qf[0] = *(const s16x8*)(qp);
    qf[1] = *(const s16x8*)(qp + 32);
  }

  // K tile 0 A-frags: row key=nt*16+l16, k-chunk kk*32+quad*8
  s16x8 kc[4][2];
#pragma unroll
  for (int nt = 0; nt < 4; nt++) {
    const unsigned short* kp = Kb + (size_t)(nt * 16 + l16) * HD + quad * 8;
    kc[nt][0] = *(const s16x8*)(kp);
    kc[nt][1] = *(const s16x8*)(kp + 32);
  }

  const s16x4 ones4 = {0x3F80, 0x3F80, 0x3F80, 0x3F80};  // bf16 1.0 x4
  f32x4 o[4] = {};   // [nd] O accum: row=q(quad*4+r), col=d(nd*16+l16)
  f32x4 lacc = {};   // row-sums, same row layout as O

  for (int kt = 0; kt <= qt; kt++) {
    // V frags for this tile (b64 x16), issued ahead of the QK compute
    s16x4 vf[4][4];
    {
      const unsigned short* vb = Vb + kt * 64 + quad * 4;
#pragma unroll
      for (int nd = 0; nd < 4; nd++)
#pragma unroll
        for (int nt = 0; nt < 4; nt++)
          vf[nd][nt] = *(const s16x4*)&vb[(size_t)(nd * 16 + l16) * T_ + nt * 16];
    }

    // S^T = K @ Q^T : m=key(64 over nt), n=q(16)
    f32x4 s[4] = {};
#pragma unroll
    for (int nt = 0; nt < 4; nt++) {
      s[nt] = MFMA32(kc[nt][0], qf[0], s[nt]);
      s[nt] = MFMA32(kc[nt][1], qf[1], s[nt]);
    }

    // software-pipeline next K tile into kc (in place after last use)
    if (kt < qt) {
      const unsigned short* kbase = Kb + (size_t)((kt + 1) * 64) * HD;
#pragma unroll
      for (int nt = 0; nt < 4; nt++) {
        const unsigned short* kp = kbase + (size_t)(nt * 16 + l16) * HD + quad * 8;
        kc[nt][0] = *(const s16x8*)(kp);
        kc[nt][1] = *(const s16x8*)(kp + 32);
      }
    }

    // p = exp2(s) (+ causal mask on diagonal tile); pf = K=16 A-frags
    s16x4 pf[4];
    if (kt < qt) {
#pragma unroll
      for (int nt = 0; nt < 4; nt++) {
        float p0 = exp2f(s[nt][0]);
        float p1 = exp2f(s[nt][1]);
        float p2 = exp2f(s[nt][2]);
        float p3 = exp2f(s[nt][3]);
        union { s16x4 v; uint2 u; } pu;
        pu.u = make_uint2(pk_bf16(p0, p1), pk_bf16(p2, p3));
        pf[nt] = pu.v;
      }
    } else {
      const int lim = wave * 16 + l16;  // keep key_local <= q_local
#pragma unroll
      for (int nt = 0; nt < 4; nt++) {
        const int kb = nt * 16 + quad * 4;
        float p0 = (kb + 0 <= lim) ? exp2f(s[nt][0]) : 0.f;
        float p1 = (kb + 1 <= lim) ? exp2f(s[nt][1]) : 0.f;
        float p2 = (kb + 2 <= lim) ? exp2f(s[nt][2]) : 0.f;
        float p3 = (kb + 3 <= lim) ? exp2f(s[nt][3]) : 0.f;
        union { s16x4 v; uint2 u; } pu;
        pu.u = make_uint2(pk_bf16(p0, p1), pk_bf16(p2, p3));
        pf[nt] = pu.v;
      }
    }

    // l += P @ 1 ; O += P @ V  (K=16 MFMAs, all operands in registers)
#pragma unroll
    for (int nt = 0; nt < 4; nt++)
      lacc = mfma16(pf[nt], ones4, lacc);
#pragma unroll
    for (int nd = 0; nd < 4; nd++)
#pragma unroll
      for (int nt = 0; nt < 4; nt++)
        o[nd] = mfma16(pf[nt], vf[nd][nt], o[nd]);
  }

  // normalize + store: O row=q(quad*4+r) contiguous in t -> float4 stores
  f32x4 inv;
#pragma unroll
  for (int r = 0; r < 4; r++) inv[r] = 1.f / lacc[r];
#pragma unroll
  for (int nd = 0; nd < 4; nd++) {
    float4 v = make_float4(o[nd][0] * inv[0], o[nd][1] * inv[1],
                           o[nd][2] * inv[2], o[nd][3] * inv[3]);
    *(float4*)(out + (size_t)bh * (HD * T_) + (size_t)(nd * 16 + l16) * T_ +
               q0 + wave * 16 + quad * 4) = v;
  }
}

extern "C" void kernel_launch(void* const* d_in, const int* in_sizes, int n_in,
                              void* d_out, int out_size, void* d_ws, size_t ws_size,
                              hipStream_t stream) {
  const float* x  = (const float*)d_in[0];
  const float* wq = (const float*)d_in[1];
  const float* wk = (const float*)d_in[2];
  const float* wv = (const float*)d_in[3];
  float* out = (float*)d_out;

  unsigned short* xb  = (unsigned short*)d_ws;       // 4194304 bf16
  unsigned short* wb  = xb + 4194304;                // 3145728 bf16 [Wq;Wk;Wv]
  unsigned short* qkv = wb + 3145728;                // 3 * 4194304 bf16

  cvt_kernel<<<7168, 256, 0, stream>>>(x, wq, wk, wv, xb, wb);
  dim3 g1(24, 32);  // N/128 x M/128
  qkv_gemm<<<g1, 256, 0, stream>>>(xb, wb, qkv);
  dim3 g2(32, 32);  // bh x qt-rev (qt descending for load balance)
  attn_kernel<<<g2, 256, 0, stream>>>(qkv, out);
}

// Round 11
// 163.119 us; speedup vs baseline: 1.8778x; 1.8778x over previous
//
#include <hip/hip_runtime.h>
#include <hip/hip_bf16.h>
#include <stdint.h>

typedef __attribute__((ext_vector_type(8))) short s16x8;
typedef __attribute__((ext_vector_type(4))) float f32x4;

#define T_   2048
#define NH   16
#define HD   64
#define DIN  1024
#define SCALE_LOG2 0.18033688011112042f  // (1/8)*log2(e)

#define MFMA32(a, b, c) __builtin_amdgcn_mfma_f32_16x16x32_bf16(a, b, c, 0, 0, 0)

// RTNE fp32 -> bf16
__device__ __forceinline__ unsigned short f2bf(float f) {
  union { float f; uint32_t u; } c; c.f = f;
  uint32_t u = c.u;
  return (unsigned short)((u + 0x7FFFu + ((u >> 16) & 1u)) >> 16);
}

__device__ __forceinline__ uint32_t pk_bf16(float a, float b) {
  __hip_bfloat162 h = __float22bfloat162_rn(make_float2(a, b));
  return *reinterpret_cast<uint32_t*>(&h);
}

// async global->LDS, 16B per lane (GEMM staging)
#define GLL(gp, lp) __builtin_amdgcn_global_load_lds( \
    (__attribute__((address_space(1))) void*)(gp),    \
    (__attribute__((address_space(3))) void*)(lp), 16, 0, 0)

// ---------------- kernel 1: fp32 -> bf16 conversion ----------------
__global__ __launch_bounds__(256) void cvt_kernel(
    const float* __restrict__ x,  const float* __restrict__ wq,
    const float* __restrict__ wk, const float* __restrict__ wv,
    unsigned short* __restrict__ xb, unsigned short* __restrict__ wb) {
  int i = (blockIdx.x * 256 + threadIdx.x) * 4;
  float4 v;
  unsigned short* dp;
  if (i < 4194304) {
    v = *(const float4*)(x + i);
    dp = xb + i;
  } else {
    int j = i - 4194304;
    int seg = j >> 20, r = j & 1048575;
    const float* w = (seg == 0) ? wq : (seg == 1) ? wk : wv;
    v = *(const float4*)(w + r);
    dp = wb + j;
  }
  ushort4 o;
  o.x = f2bf(v.x); o.y = f2bf(v.y); o.z = f2bf(v.z); o.w = f2bf(v.w);
  *(ushort4*)dp = o;
}

// ---------------- kernel 2: QKV projection GEMM (round-7, unchanged) -------
__global__ __launch_bounds__(256) void qkv_gemm(
    const unsigned short* __restrict__ A, const unsigned short* __restrict__ Bm,
    unsigned short* __restrict__ qkv) {
  __shared__ __attribute__((aligned(16))) unsigned short Alds[128 * 64];
  __shared__ __attribute__((aligned(16))) unsigned short Blds[128 * 64];
  const int tid = threadIdx.x;
  const int lane = tid & 63, wave = tid >> 6;
  const int wm = wave >> 1, wn = wave & 1;
  const int m0 = blockIdx.y * 128, n0 = blockIdx.x * 128;

  f32x4 acc[4][4] = {};

  const int srow = wave * 32 + (lane >> 3);
  const int scol = (((lane & 7) ^ ((lane >> 3) & 7))) * 8;
  const unsigned short* ag = A  + (size_t)(m0 + srow) * DIN + scol;
  const unsigned short* bg = Bm + (size_t)(n0 + srow) * DIN + scol;
  unsigned short* al = &Alds[wave * 32 * 64];
  unsigned short* bl = &Blds[wave * 32 * 64];

  const int l16 = lane & 15, quad = lane >> 4;
  const int sw = l16 & 7;

  for (int k0 = 0; k0 < DIN; k0 += 64) {
    __syncthreads();
#pragma unroll
    for (int i = 0; i < 4; i++) {
      GLL(ag + (size_t)i * 8 * DIN + k0, al + i * 512);
      GLL(bg + (size_t)i * 8 * DIN + k0, bl + i * 512);
    }
    __syncthreads();
#pragma unroll
    for (int ks = 0; ks < 2; ks++) {
      const int cl = ((ks * 4 + quad) ^ sw) * 8;
      s16x8 af[4], bf[4];
#pragma unroll
      for (int mt = 0; mt < 4; mt++)
        af[mt] = *(const s16x8*)&Alds[(wm * 64 + mt * 16 + l16) * 64 + cl];
#pragma unroll
      for (int nt = 0; nt < 4; nt++)
        bf[nt] = *(const s16x8*)&Blds[(wn * 64 + nt * 16 + l16) * 64 + cl];
#pragma unroll
      for (int mt = 0; mt < 4; mt++)
#pragma unroll
        for (int nt = 0; nt < 4; nt++)
          acc[mt][nt] = MFMA32(af[mt], bf[nt], acc[mt][nt]);
    }
  }

#pragma unroll
  for (int mt = 0; mt < 4; mt++) {
    int mbase = m0 + wm * 64 + mt * 16 + (quad << 2);
    int b = mbase >> 11, t = mbase & 2047;
#pragma unroll
    for (int nt = 0; nt < 4; nt++) {
      int n = n0 + wn * 64 + nt * 16 + l16;
      int sel = n >> 10, h = (n >> 6) & 15, d = n & 63;
      int bh = b * NH + h;
      if (sel == 2) {
        ushort4 pk;
        pk.x = f2bf(acc[mt][nt][0]); pk.y = f2bf(acc[mt][nt][1]);
        pk.z = f2bf(acc[mt][nt][2]); pk.w = f2bf(acc[mt][nt][3]);
        *(ushort4*)&qkv[8388608 + (size_t)(bh * HD + d) * T_ + t] = pk;
      } else {
        float qs = (sel == 0) ? SCALE_LOG2 : 1.f;
#pragma unroll
        for (int r = 0; r < 4; r++)
          qkv[(size_t)sel * 4194304 + (size_t)(bh * T_ + t + r) * HD + d] =
              f2bf(acc[mt][nt][r] * qs);
      }
    }
  }
}

// ---------------- kernel 3: causal flash attention ----------------
// Round-7 structure at 2 waves / 32-q tiles: grid 32bh x 64qt' = 2048 blocks
// -> 8 resident blocks/CU (LDS 20.5KB) instead of 4 (grid-capped before).
// Wave w owns q rows [q0+16w, q0+16w+16). Q pre-scaled -> p = exp2(s).
// S^T = K·Q^T; P through swizzled LDS; row-sums via ones-MFMA; stride-64
// XOR-swizzled LDS rows (all b128, conflict-free).
__global__ __launch_bounds__(128) void attn_kernel(
    const unsigned short* __restrict__ qkv, float* __restrict__ out) {
  __shared__ __attribute__((aligned(16))) unsigned short Klds[64 * 64];
  __shared__ __attribute__((aligned(16))) unsigned short Vt[64 * 64];
  __shared__ __attribute__((aligned(16))) unsigned short Plds[2 * 16 * 64];

  const int lane = threadIdx.x & 63, wave = threadIdx.x >> 6;
  const int l16 = lane & 15, quad = lane >> 4;
  const int swl = l16 & 7;
  const int qt = 63 - blockIdx.y, bh = blockIdx.x;
  const int q0 = qt * 32;
  const int qw = q0 + wave * 16;              // this wave's first q row
  const int ktmax = (q0 + 31) >> 6;           // last key-tile this block needs
  const size_t bh_off = (size_t)bh * (T_ * HD);
  const unsigned short* Q  = qkv + bh_off;            // [t][d], pre-scaled
  const unsigned short* Kb = qkv + 4194304 + bh_off;  // [t][d]
  const unsigned short* Vb = qkv + 8388608 + bh_off;  // [d][t]

  s16x8 qf[2];
  {
    const unsigned short* qp = Q + (size_t)(qw + l16) * HD + quad * 8;
    qf[0] = *(const s16x8*)(qp);
    qf[1] = *(const s16x8*)(qp + 32);
  }

  const int sr = threadIdx.x >> 3;                       // staging row 0..15
  const int sc = (threadIdx.x & 7) * 8;                  // linear global chunk
  const int swc = (((threadIdx.x & 7) ^ (sr & 7))) * 8;  // swizzled LDS chunk

  // prefetch tile 0: 4 K rows + 4 V rows per thread (rows sr+16i)
  s16x8 kr[4], vr[4];
#pragma unroll
  for (int i = 0; i < 4; i++) {
    kr[i] = *(const s16x8*)&Kb[(size_t)(sr + 16 * i) * HD + sc];
    vr[i] = *(const s16x8*)&Vb[(size_t)(sr + 16 * i) * T_ + sc];
  }

  const s16x8 onesf = {0x3F80, 0x3F80, 0x3F80, 0x3F80,
                       0x3F80, 0x3F80, 0x3F80, 0x3F80};  // bf16 1.0 x8
  f32x4 o[4] = {};
  f32x4 lacc = {};

  uint32_t* prow = (uint32_t*)&Plds[(wave * 16 + l16) * 64];
  const unsigned short* prd = &Plds[(wave * 16 + l16) * 64];

  for (int kt = 0; kt <= ktmax; kt++) {
    __syncthreads();
#pragma unroll
    for (int i = 0; i < 4; i++) {
      *(s16x8*)&Klds[(sr + 16 * i) * 64 + swc] = kr[i];
      *(s16x8*)&Vt[(sr + 16 * i) * 64 + swc] = vr[i];
    }
    if (kt < ktmax) {
      const unsigned short* kp = Kb + (size_t)(kt + 1) * 64 * HD;
      const unsigned short* vp = Vb + (kt + 1) * 64;
#pragma unroll
      for (int i = 0; i < 4; i++) {
        kr[i] = *(const s16x8*)&kp[(size_t)(sr + 16 * i) * HD + sc];
        vr[i] = *(const s16x8*)&vp[(size_t)(sr + 16 * i) * T_ + sc];
      }
    }
    __syncthreads();

    // S^T = K @ Q^T : m=key, n=q
    f32x4 s[4] = {};
#pragma unroll
    for (int kk = 0; kk < 2; kk++) {
      const int cl = ((kk * 4 + quad) ^ swl) * 8;
#pragma unroll
      for (int nt = 0; nt < 4; nt++) {
        s16x8 kf = *(const s16x8*)&Klds[(nt * 16 + l16) * 64 + cl];
        s[nt] = MFMA32(kf, qf[kk], s[nt]);
      }
    }

    // p = exp2(s); mask only on tiles crossing this wave's diagonal
    if (kt * 64 + 63 <= qw) {  // fully visible
#pragma unroll
      for (int nt = 0; nt < 4; nt++) {
        float p0 = exp2f(s[nt][0]);
        float p1 = exp2f(s[nt][1]);
        float p2 = exp2f(s[nt][2]);
        float p3 = exp2f(s[nt][3]);
        *(uint2*)&prow[(((2 * nt + (quad >> 1)) ^ swl) << 2) + (quad & 1) * 2] =
            make_uint2(pk_bf16(p0, p1), pk_bf16(p2, p3));
      }
    } else {  // diagonal-crossing tile
      const int lim = qw + l16 - kt * 64;  // keep key_local <= lim
#pragma unroll
      for (int nt = 0; nt < 4; nt++) {
        const int kb = nt * 16 + quad * 4;
        float p0 = (kb + 0 <= lim) ? exp2f(s[nt][0]) : 0.f;
        float p1 = (kb + 1 <= lim) ? exp2f(s[nt][1]) : 0.f;
        float p2 = (kb + 2 <= lim) ? exp2f(s[nt][2]) : 0.f;
        float p3 = (kb + 3 <= lim) ? exp2f(s[nt][3]) : 0.f;
        *(uint2*)&prow[(((2 * nt + (quad >> 1)) ^ swl) << 2) + (quad & 1) * 2] =
            make_uint2(pk_bf16(p0, p1), pk_bf16(p2, p3));
      }
    }

    // O += P @ V ; l += P @ 1
#pragma unroll
    for (int kk = 0; kk < 2; kk++) {
      const int cl = ((kk * 4 + quad) ^ swl) * 8;
      s16x8 pf = *(const s16x8*)&prd[cl];
      lacc = MFMA32(pf, onesf, lacc);
#pragma unroll
      for (int dt = 0; dt < 4; dt++) {
        s16x8 vf = *(const s16x8*)&Vt[(dt * 16 + l16) * 64 + cl];
        o[dt] = MFMA32(pf, vf, o[dt]);
      }
    }
  }

  // normalize + store: lacc row=quad*4+r matches O rows exactly
  f32x4 inv;
#pragma unroll
  for (int r = 0; r < 4; r++) inv[r] = 1.f / lacc[r];
#pragma unroll
  for (int dt = 0; dt < 4; dt++) {
    float4 v = make_float4(o[dt][0] * inv[0], o[dt][1] * inv[1],
                           o[dt][2] * inv[2], o[dt][3] * inv[3]);
    *(float4*)(out + (size_t)bh * (HD * T_) + (size_t)(dt * 16 + l16) * T_ +
               qw + quad * 4) = v;
  }
}

extern "C" void kernel_launch(void* const* d_in, const int* in_sizes, int n_in,
                              void* d_out, int out_size, void* d_ws, size_t ws_size,
                              hipStream_t stream) {
  const float* x  = (const float*)d_in[0];
  const float* wq = (const float*)d_in[1];
  const float* wk = (const float*)d_in[2];
  const float* wv = (const float*)d_in[3];
  float* out = (float*)d_out;

  unsigned short* xb  = (unsigned short*)d_ws;       // 4194304 bf16
  unsigned short* wb  = xb + 4194304;                // 3145728 bf16 [Wq;Wk;Wv]
  unsigned short* qkv = wb + 3145728;                // 3 * 4194304 bf16

  cvt_kernel<<<7168, 256, 0, stream>>>(x, wq, wk, wv, xb, wb);
  dim3 g1(24, 32);  // N/128 x M/128
  qkv_gemm<<<g1, 256, 0, stream>>>(xb, wb, qkv);
  dim3 g2(32, 64);  // bh x qt'-rev (32-q tiles, descending for load balance)
  attn_kernel<<<g2, 128, 0, stream>>>(qkv, out);
}

// Round 12
// 150.478 us; speedup vs baseline: 2.0355x; 1.0840x over previous
//
#include <hip/hip_runtime.h>
#include <hip/hip_bf16.h>
#include <stdint.h>

typedef __attribute__((ext_vector_type(8))) short s16x8;
typedef __attribute__((ext_vector_type(4))) float f32x4;

#define T_   2048
#define NH   16
#define HD   64
#define DIN  1024
#define SCALE_LOG2 0.18033688011112042f  // (1/8)*log2(e)

#define MFMA32(a, b, c) __builtin_amdgcn_mfma_f32_16x16x32_bf16(a, b, c, 0, 0, 0)

// RTNE fp32 -> bf16
__device__ __forceinline__ unsigned short f2bf(float f) {
  union { float f; uint32_t u; } c; c.f = f;
  uint32_t u = c.u;
  return (unsigned short)((u + 0x7FFFu + ((u >> 16) & 1u)) >> 16);
}

__device__ __forceinline__ uint32_t pk_bf16(float a, float b) {
  __hip_bfloat162 h = __float22bfloat162_rn(make_float2(a, b));
  return *reinterpret_cast<uint32_t*>(&h);
}

// async global->LDS, 16B per lane; dest = wave-uniform base + lane*16
#define GLL(gp, lp) __builtin_amdgcn_global_load_lds( \
    (__attribute__((address_space(1))) void*)(gp),    \
    (__attribute__((address_space(3))) void*)(lp), 16, 0, 0)

// ---------------- kernel 1: fp32 -> bf16 conversion ----------------
__global__ __launch_bounds__(256) void cvt_kernel(
    const float* __restrict__ x,  const float* __restrict__ wq,
    const float* __restrict__ wk, const float* __restrict__ wv,
    unsigned short* __restrict__ xb, unsigned short* __restrict__ wb) {
  int i = (blockIdx.x * 256 + threadIdx.x) * 4;
  float4 v;
  unsigned short* dp;
  if (i < 4194304) {
    v = *(const float4*)(x + i);
    dp = xb + i;
  } else {
    int j = i - 4194304;
    int seg = j >> 20, r = j & 1048575;
    const float* w = (seg == 0) ? wq : (seg == 1) ? wk : wv;
    v = *(const float4*)(w + r);
    dp = wb + j;
  }
  ushort4 o;
  o.x = f2bf(v.x); o.y = f2bf(v.y); o.z = f2bf(v.z); o.w = f2bf(v.w);
  *(ushort4*)dp = o;
}

// ---------------- kernel 2: QKV projection GEMM ----------------
// 64x128 (MxN) tiles -> grid 24x64 = 1536 blocks = 6 blocks/CU (was 3:
// grid-starved, MfmaUtil 17 / Occ 13 with all pipes idle = latency-bound).
// LDS 24KB/block = exactly 6 resident; acc 32 VGPR/wave. XOR-swizzled LDS,
// all-b128, GLL staging. Epilogue: Q pre-scaled; V transposed [bh][d][t].
__global__ __launch_bounds__(256) void qkv_gemm(
    const unsigned short* __restrict__ A, const unsigned short* __restrict__ Bm,
    unsigned short* __restrict__ qkv) {
  __shared__ __attribute__((aligned(16))) unsigned short Alds[64 * 64];
  __shared__ __attribute__((aligned(16))) unsigned short Blds[128 * 64];
  const int tid = threadIdx.x;
  const int lane = tid & 63, wave = tid >> 6;
  const int wm = wave >> 1, wn = wave & 1;  // 2x2 waves over 64x128
  const int m0 = blockIdx.y * 64, n0 = blockIdx.x * 128;

  f32x4 acc[2][4] = {};

  const int srA = wave * 16 + (lane >> 3);  // A staging row (2 issues x 8)
  const int srB = wave * 32 + (lane >> 3);  // B staging row (4 issues x 8)
  const int scol = (((lane & 7) ^ ((lane >> 3) & 7))) * 8;
  const unsigned short* ag = A  + (size_t)(m0 + srA) * DIN + scol;
  const unsigned short* bg = Bm + (size_t)(n0 + srB) * DIN + scol;
  unsigned short* al = &Alds[wave * 16 * 64];
  unsigned short* bl = &Blds[wave * 32 * 64];

  const int l16 = lane & 15, quad = lane >> 4;
  const int sw = l16 & 7;

  for (int k0 = 0; k0 < DIN; k0 += 64) {
    __syncthreads();
#pragma unroll
    for (int i = 0; i < 2; i++)
      GLL(ag + (size_t)i * 8 * DIN + k0, al + i * 512);
#pragma unroll
    for (int i = 0; i < 4; i++)
      GLL(bg + (size_t)i * 8 * DIN + k0, bl + i * 512);
    __syncthreads();
#pragma unroll
    for (int ks = 0; ks < 2; ks++) {
      const int cl = ((ks * 4 + quad) ^ sw) * 8;
      s16x8 af[2], bf[4];
#pragma unroll
      for (int mt = 0; mt < 2; mt++)
        af[mt] = *(const s16x8*)&Alds[(wm * 32 + mt * 16 + l16) * 64 + cl];
#pragma unroll
      for (int nt = 0; nt < 4; nt++)
        bf[nt] = *(const s16x8*)&Blds[(wn * 64 + nt * 16 + l16) * 64 + cl];
#pragma unroll
      for (int mt = 0; mt < 2; mt++)
#pragma unroll
        for (int nt = 0; nt < 4; nt++)
          acc[mt][nt] = MFMA32(af[mt], bf[nt], acc[mt][nt]);
    }
  }

#pragma unroll
  for (int mt = 0; mt < 2; mt++) {
    int mbase = m0 + wm * 32 + mt * 16 + (quad << 2);
    int b = mbase >> 11, t = mbase & 2047;
#pragma unroll
    for (int nt = 0; nt < 4; nt++) {
      int n = n0 + wn * 64 + nt * 16 + l16;
      int sel = n >> 10, h = (n >> 6) & 15, d = n & 63;
      int bh = b * NH + h;
      if (sel == 2) {
        ushort4 pk;
        pk.x = f2bf(acc[mt][nt][0]); pk.y = f2bf(acc[mt][nt][1]);
        pk.z = f2bf(acc[mt][nt][2]); pk.w = f2bf(acc[mt][nt][3]);
        *(ushort4*)&qkv[8388608 + (size_t)(bh * HD + d) * T_ + t] = pk;
      } else {
        float qs = (sel == 0) ? SCALE_LOG2 : 1.f;  // fold softmax scale into Q
#pragma unroll
        for (int r = 0; r < 4; r++)
          qkv[(size_t)sel * 4194304 + (size_t)(bh * T_ + t + r) * HD + d] =
              f2bf(acc[mt][nt][r] * qs);
      }
    }
  }
}

// ---------------- kernel 3: causal flash attention (round-7 exact) ---------
// 64-q blocks (grid 32x32, qt descending). 4 waves x 16 q. Q pre-scaled ->
// p = exp2(s). S^T = K·Q^T. Row-sums via ones-MFMA (l lands in O's register
// layout). Mask only on diagonal tile. Stride-64 XOR-swizzled LDS rows
// (16B-aligned -> all ds b128, conflict-free).
__global__ __launch_bounds__(256) void attn_kernel(
    const unsigned short* __restrict__ qkv, float* __restrict__ out) {
  __shared__ __attribute__((aligned(16))) unsigned short Klds[64 * 64];
  __shared__ __attribute__((aligned(16))) unsigned short Vt[64 * 64];
  __shared__ __attribute__((aligned(16))) unsigned short Plds[64 * 64];

  const int lane = threadIdx.x & 63, wave = threadIdx.x >> 6;
  const int l16 = lane & 15, quad = lane >> 4;
  const int swl = l16 & 7;
  const int qt = 31 - blockIdx.y, bh = blockIdx.x;
  const int q0 = qt * 64;
  const size_t bh_off = (size_t)bh * (T_ * HD);
  const unsigned short* Q  = qkv + bh_off;            // [t][d], pre-scaled
  const unsigned short* Kb = qkv + 4194304 + bh_off;  // [t][d]
  const unsigned short* Vb = qkv + 8388608 + bh_off;  // [d][t]

  s16x8 qf[2];
  {
    const unsigned short* qp =
        Q + (size_t)(q0 + wave * 16 + l16) * HD + quad * 8;
    qf[0] = *(const s16x8*)(qp);
    qf[1] = *(const s16x8*)(qp + 32);
  }

  const int sr = threadIdx.x >> 3;                 // staging row 0..31
  const int sc = (threadIdx.x & 7) * 8;            // linear global chunk
  const int swc = (((threadIdx.x & 7) ^ (sr & 7))) * 8;  // swizzled LDS chunk

  s16x8 kr0 = *(const s16x8*)&Kb[(size_t)sr * HD + sc];
  s16x8 kr1 = *(const s16x8*)&Kb[(size_t)(sr + 32) * HD + sc];
  s16x8 vr0 = *(const s16x8*)&Vb[(size_t)sr * T_ + sc];
  s16x8 vr1 = *(const s16x8*)&Vb[(size_t)(sr + 32) * T_ + sc];

  const s16x8 onesf = {0x3F80, 0x3F80, 0x3F80, 0x3F80,
                       0x3F80, 0x3F80, 0x3F80, 0x3F80};  // bf16 1.0 x8
  f32x4 o[4] = {};
  f32x4 lacc = {};

  uint32_t* prow = (uint32_t*)&Plds[(wave * 16 + l16) * 64];
  const unsigned short* prd = &Plds[(wave * 16 + l16) * 64];

  for (int kt = 0; kt <= qt; kt++) {
    __syncthreads();
    *(s16x8*)&Klds[sr * 64 + swc] = kr0;
    *(s16x8*)&Klds[(sr + 32) * 64 + swc] = kr1;
    *(s16x8*)&Vt[sr * 64 + swc] = vr0;
    *(s16x8*)&Vt[(sr + 32) * 64 + swc] = vr1;
    if (kt < qt) {
      const unsigned short* kp = Kb + (size_t)(kt + 1) * 64 * HD;
      const unsigned short* vp = Vb + (kt + 1) * 64;
      kr0 = *(const s16x8*)&kp[(size_t)sr * HD + sc];
      kr1 = *(const s16x8*)&kp[(size_t)(sr + 32) * HD + sc];
      vr0 = *(const s16x8*)&vp[(size_t)sr * T_ + sc];
      vr1 = *(const s16x8*)&vp[(size_t)(sr + 32) * T_ + sc];
    }
    __syncthreads();

    // S^T = K @ Q^T : m=key, n=q
    f32x4 s[4] = {};
#pragma unroll
    for (int kk = 0; kk < 2; kk++) {
      const int cl = ((kk * 4 + quad) ^ swl) * 8;
#pragma unroll
      for (int nt = 0; nt < 4; nt++) {
        s16x8 kf = *(const s16x8*)&Klds[(nt * 16 + l16) * 64 + cl];
        s[nt] = MFMA32(kf, qf[kk], s[nt]);
      }
    }

    // P write: logical chunk 2nt+(quad>>1), phys = ^(l16&7), inner (quad&1)*2
    if (kt < qt) {  // fully visible tile: no mask code
#pragma unroll
      for (int nt = 0; nt < 4; nt++) {
        float p0 = exp2f(s[nt][0]);
        float p1 = exp2f(s[nt][1]);
        float p2 = exp2f(s[nt][2]);
        float p3 = exp2f(s[nt][3]);
        *(uint2*)&prow[(((2 * nt + (quad >> 1)) ^ swl) << 2) + (quad & 1) * 2] =
            make_uint2(pk_bf16(p0, p1), pk_bf16(p2, p3));
      }
    } else {  // diagonal tile: causal mask
      const int lim = wave * 16 + l16;
#pragma unroll
      for (int nt = 0; nt < 4; nt++) {
        const int kb = nt * 16 + quad * 4;
        float p0 = (kb + 0 <= lim) ? exp2f(s[nt][0]) : 0.f;
        float p1 = (kb + 1 <= lim) ? exp2f(s[nt][1]) : 0.f;
        float p2 = (kb + 2 <= lim) ? exp2f(s[nt][2]) : 0.f;
        float p3 = (kb + 3 <= lim) ? exp2f(s[nt][3]) : 0.f;
        *(uint2*)&prow[(((2 * nt + (quad >> 1)) ^ swl) << 2) + (quad & 1) * 2] =
            make_uint2(pk_bf16(p0, p1), pk_bf16(p2, p3));
      }
    }

    // O += P @ V ; l += P @ 1
#pragma unroll
    for (int kk = 0; kk < 2; kk++) {
      const int cl = ((kk * 4 + quad) ^ swl) * 8;
      s16x8 pf = *(const s16x8*)&prd[cl];
      lacc = MFMA32(pf, onesf, lacc);
#pragma unroll
      for (int dt = 0; dt < 4; dt++) {
        s16x8 vf = *(const s16x8*)&Vt[(dt * 16 + l16) * 64 + cl];
        o[dt] = MFMA32(pf, vf, o[dt]);
      }
    }
  }

  // normalize + store: lacc row=quad*4+r matches O rows exactly
  f32x4 inv;
#pragma unroll
  for (int r = 0; r < 4; r++) inv[r] = 1.f / lacc[r];
#pragma unroll
  for (int dt = 0; dt < 4; dt++) {
    float4 v = make_float4(o[dt][0] * inv[0], o[dt][1] * inv[1],
                           o[dt][2] * inv[2], o[dt][3] * inv[3]);
    *(float4*)(out + (size_t)bh * (HD * T_) + (size_t)(dt * 16 + l16) * T_ +
               q0 + wave * 16 + quad * 4) = v;
  }
}

extern "C" void kernel_launch(void* const* d_in, const int* in_sizes, int n_in,
                              void* d_out, int out_size, void* d_ws, size_t ws_size,
                              hipStream_t stream) {
  const float* x  = (const float*)d_in[0];
  const float* wq = (const float*)d_in[1];
  const float* wk = (const float*)d_in[2];
  const float* wv = (const float*)d_in[3];
  float* out = (float*)d_out;

  unsigned short* xb  = (unsigned short*)d_ws;       // 4194304 bf16
  unsigned short* wb  = xb + 4194304;                // 3145728 bf16 [Wq;Wk;Wv]
  unsigned short* qkv = wb + 3145728;                // 3 * 4194304 bf16

  cvt_kernel<<<7168, 256, 0, stream>>>(x, wq, wk, wv, xb, wb);
  dim3 g1(24, 64);  // N/128 x M/64 -> 1536 blocks, 6/CU
  qkv_gemm<<<g1, 256, 0, stream>>>(xb, wb, qkv);
  dim3 g2(32, 32);  // bh x qt-rev (64-q tiles, descending for load balance)
  attn_kernel<<<g2, 256, 0, stream>>>(qkv, out);
}